// Round 11
// baseline (236.925 us; speedup 1.0000x reference)
//
#include <hip/hip_runtime.h>
#include <stdint.h>

typedef __attribute__((ext_vector_type(8))) short short8;
typedef __attribute__((ext_vector_type(4))) float floatx4;

static inline size_t align256(size_t x) { return (x + 255) & ~size_t(255); }

__device__ __forceinline__ unsigned short f2bf(float f) {
    unsigned u = __float_as_uint(f);
    u += 0x7fff + ((u >> 16) & 1);     // round-to-nearest-even
    return (unsigned short)(u >> 16);
}
__device__ __forceinline__ unsigned pack_bf16(float a, float b) {
    return (unsigned)f2bf(a) | ((unsigned)f2bf(b) << 16);
}
__device__ __forceinline__ float bf_lo(unsigned u) { return __uint_as_float(u << 16); }
__device__ __forceinline__ float bf_hi(unsigned u) { return __uint_as_float(u & 0xffff0000u); }

#define BSHIFT 7     // 128 nodes per dst-bucket
#define NBMAX 1024   // max buckets per LDS window
#define CH 2048      // edges per chunk
#define SCAP 3072    // LDS-staged pairs per bucket
// bbuf packing: (dst&127)<<25 | src  -- requires N < 2^25 (here N=50000)

// per-block edge dtype self-detection: int32 data read as int64 pairs gives
// out-of-range values with prob ~1 per sample; 256 samples => certain.
__device__ __forceinline__ bool detect_i32(const void* eidx, int E, int t) {
    const long long* e64 = (const long long*)eidx;
    int nchk = E < 256 ? E : 256;
    long long v = e64[t % nchk];
    int bad = (v < 0 || v > 0x7fffffffLL) ? 1 : 0;
    return __syncthreads_or(bad) != 0;
}

// ---- chunk x bucket histogram (LDS only); blocks NC/NC+1 convert W1/W2 ----
__global__ __launch_bounds__(256) void k_hist(const void* __restrict__ eidx, int E,
        int* __restrict__ chist, int NB, int NC,
        const float* __restrict__ W1, const float* __restrict__ W2,
        unsigned short* __restrict__ w1t, unsigned short* __restrict__ w2t,
        int K1, int M1, int K2, int M2) {
    __shared__ int hist[NBMAX];
    const int t = threadIdx.x, B = blockIdx.x;
    if (B < NC) {
        const int e0 = B * CH;
        const int e1 = (e0 + CH < E) ? e0 + CH : E;
        const bool i32 = detect_i32(eidx, E, t);
        const int* e32 = (const int*)eidx;
        const long long* e64 = (const long long*)eidx;
        for (int b0 = 0; b0 < NB; b0 += NBMAX) {
            int bw = (NB - b0 < NBMAX) ? NB - b0 : NBMAX;
            for (int i = t; i < bw; i += 256) hist[i] = 0;
            __syncthreads();
            for (int e = e0 + t; e < e1; e += 256) {
                int d = i32 ? e32[(size_t)E + e] : (int)e64[(size_t)E + e];
                int b = (d >> BSHIFT) - b0;
                if (b >= 0 && b < bw) atomicAdd(&hist[b], 1);
            }
            __syncthreads();
            for (int i = t; i < bw; i += 256) chist[(size_t)(b0 + i) * NC + B] = hist[i];
            __syncthreads();
        }
    } else if (B == NC) {
        for (int j = t; j < K1 * M1; j += 256) {
            int k = j / M1, n = j % M1;
            w1t[(size_t)n * K1 + k] = f2bf(W1[j]);
        }
    } else if (B == NC + 1) {
        for (int j = t; j < K2 * M2; j += 256) {
            int k = j / M2, n = j % M2;
            w2t[(size_t)n * K2 + k] = f2bf(W2[j]);
        }
    }
}

// ---- merged: bucket row-sums (wave per bucket) + single-block scan -> bbase.
//      Requires NB <= 1024. ----
__global__ __launch_bounds__(1024) void k_bscan(const int* __restrict__ chist,
                                                int* __restrict__ bbase,
                                                int* __restrict__ rs_final,
                                                int NB, int NC, int N) {
    __shared__ int tot[1024];
    __shared__ int swt[16];
    const int t = threadIdx.x, lane = t & 63, w = t >> 6;
    for (int b = w; b < NB; b += 16) {
        const int* row = chist + (size_t)b * NC;
        int v = 0;
        for (int i = lane; i < NC; i += 64) v += row[i];
        #pragma unroll
        for (int off = 32; off >= 1; off >>= 1) v += __shfl_xor(v, off, 64);
        if (lane == 0) tot[b] = v;
    }
    __syncthreads();
    int v = (t < NB) ? tot[t] : 0;
    int incl = v;
    #pragma unroll
    for (int off = 1; off < 64; off <<= 1) {
        int nbr = __shfl_up(incl, off, 64);
        if (lane >= off) incl += nbr;
    }
    if (lane == 63) swt[w] = incl;
    __syncthreads();
    int woff = 0;
    for (int j = 0; j < w; ++j) woff += swt[j];
    if (t < NB) bbase[t] = woff + incl - v;
    if (t == 1023) {
        int total = woff + incl;
        bbase[NB] = total;
        rs_final[N] = total;
    }
}

// ---- per-bucket chunk scan seeded with bbase: chist[b][c] -> global slot base ----
__global__ __launch_bounds__(256) void k_hscan2(int* __restrict__ chist,
                                                const int* __restrict__ bbase,
                                                int NB, int NC) {
    int b = blockIdx.x * 4 + (threadIdx.x >> 6);
    if (b >= NB) return;
    int lane = threadIdx.x & 63;
    int* row = chist + (size_t)b * NC;
    int carry = bbase[b];
    for (int base = 0; base < NC; base += 64) {
        int i = base + lane;
        int v = (i < NC) ? row[i] : 0;
        int incl = v;
        #pragma unroll
        for (int off = 1; off < 64; off <<= 1) {
            int nbr = __shfl_up(incl, off, 64);
            if (lane >= off) incl += nbr;
        }
        if (i < NC) row[i] = carry + incl - v;
        carry += __shfl(incl, 63, 64);
    }
}

// ---- binned fill: deterministic base + LDS rank; packed uint payload ----
__global__ __launch_bounds__(256) void k_bfill(const void* __restrict__ eidx, int E,
                                               const int* __restrict__ chist,
                                               unsigned* __restrict__ bbuf, int NB, int NC) {
    __shared__ int rank[NBMAX];
    __shared__ int base[NBMAX];
    const int t = threadIdx.x, c = blockIdx.x;
    const int e0 = c * CH;
    const int e1 = (e0 + CH < E) ? e0 + CH : E;
    const bool i32 = detect_i32(eidx, E, t);
    const int* e32 = (const int*)eidx;
    const long long* e64 = (const long long*)eidx;
    for (int b0 = 0; b0 < NB; b0 += NBMAX) {
        int bw = (NB - b0 < NBMAX) ? NB - b0 : NBMAX;
        for (int i = t; i < bw; i += 256) {
            rank[i] = 0;
            base[i] = chist[(size_t)(b0 + i) * NC + c];
        }
        __syncthreads();
        for (int e = e0 + t; e < e1; e += 256) {
            int s, d;
            if (i32) { s = e32[e]; d = e32[(size_t)E + e]; }
            else     { s = (int)e64[e]; d = (int)e64[(size_t)E + e]; }
            int b = (d >> BSHIFT) - b0;
            if (b >= 0 && b < bw) {
                int slot = base[b] + atomicAdd(&rank[b], 1);
                bbuf[slot] = ((unsigned)(d & 127) << 25) | (unsigned)s;
            }
        }
        __syncthreads();
    }
}

// ---- per-bucket LDS counting sort: emits esrc (coalesced), rs_final, dinv ----
__global__ __launch_bounds__(256) void k_sort(const unsigned* __restrict__ bbuf,
                                              const int* __restrict__ bbase,
                                              int* __restrict__ rs_final,
                                              float* __restrict__ dinv,
                                              int* __restrict__ esrc, int N) {
    __shared__ int hist[128];
    __shared__ int off[128];
    __shared__ int srcbuf[SCAP];
    const int b = blockIdx.x, t = threadIdx.x;
    const int node0 = b << BSHIFT;
    const int nloc = (N - node0 < 128) ? N - node0 : 128;
    const int s0 = bbase[b], s1 = bbase[b + 1];
    const int cnt = s1 - s0;
    if (t < 128) hist[t] = 0;
    __syncthreads();
    for (int i = s0 + t; i < s1; i += 256)
        atomicAdd(&hist[bbuf[i] >> 25], 1);
    __syncthreads();
    if (t < 64) {   // wave 0: exclusive scan of 128 counts
        int carry = 0;
        #pragma unroll
        for (int base = 0; base < 128; base += 64) {
            int v = hist[base + t];
            int incl = v;
            #pragma unroll
            for (int o = 1; o < 64; o <<= 1) {
                int nbr = __shfl_up(incl, o, 64);
                if (t >= o) incl += nbr;
            }
            off[base + t] = carry + incl - v;
            carry += __shfl(incl, 63, 64);
        }
    }
    __syncthreads();
    if (t < nloc) {
        rs_final[node0 + t] = s0 + off[t];
        dinv[node0 + t] = rsqrtf((float)hist[t] + 1.0f);
    }
    __syncthreads();
    if (t < 128) hist[t] = 0;   // reuse as rank counters
    __syncthreads();
    if (cnt <= SCAP) {
        for (int i = s0 + t; i < s1; i += 256) {
            unsigned sd = bbuf[i];
            int lo = sd >> 25;
            int r = atomicAdd(&hist[lo], 1);
            srcbuf[off[lo] + r] = (int)(sd & 0x1ffffffu);
        }
        __syncthreads();
        for (int i = t; i < cnt; i += 256) esrc[s0 + i] = srcbuf[i];
    } else {        // fallback: scatter within bucket's global window
        for (int i = s0 + t; i < s1; i += 256) {
            unsigned sd = bbuf[i];
            int lo = sd >> 25;
            int r = atomicAdd(&hist[lo], 1);
            esrc[s0 + off[lo] + r] = (int)(sd & 0x1ffffffu);
        }
    }
}

// ============================================================================
// bf16 MFMA GEMM, tile 64 rows x BN cols (BN == M), K=128 one LDS stage.
// AF32: A is fp32, converted during staging. Epilogue folds dinv.
// ============================================================================
template<int BN, bool AF32>
__global__ __launch_bounds__(256, 3) void k_gemm(
        const void* __restrict__ Av, const unsigned short* __restrict__ Bt,
        const float* __restrict__ dinv, unsigned short* __restrict__ C,
        int N, int M) {
    constexpr int LD = 136;               // 128 + 8 u16 pad
    __shared__ unsigned short As[64 * LD];
    __shared__ unsigned short Bs[BN * LD];
    const int tid = threadIdx.x;
    const int wave = tid >> 6, lane = tid & 63;
    const int q = lane >> 4, tm = lane & 15;
    const int row0 = blockIdx.x * 64;

    {   // stage Bt rows [0,BN)
        const uint4* Bg = (const uint4*)Bt;
        #pragma unroll
        for (int it = 0; it < BN / 16; ++it) {
            int i = tid + it * 256;
            int r = i >> 4, o = i & 15;
            *(uint4*)&Bs[r * LD + o * 8] = Bg[(size_t)r * 16 + o];
        }
    }
    if (AF32) {   // stage A rows with inline fp32->bf16
        const float4* Ag = (const float4*)Av;
        #pragma unroll
        for (int it = 0; it < 8; ++it) {
            int i = tid + it * 256;
            int r = i >> 5, o = i & 31;
            int row = row0 + r;
            float4 v = make_float4(0.f, 0.f, 0.f, 0.f);
            if (row < N) v = Ag[(size_t)row * 32 + o];
            uint2 pk;
            pk.x = pack_bf16(v.x, v.y);
            pk.y = pack_bf16(v.z, v.w);
            *(uint2*)&As[r * LD + o * 4] = pk;
        }
    } else {      // stage bf16 A rows
        const uint4* Ag = (const uint4*)Av;
        #pragma unroll
        for (int it = 0; it < 4; ++it) {
            int i = tid + it * 256;
            int r = i >> 4, o = i & 15;
            int row = row0 + r;
            uint4 v = make_uint4(0, 0, 0, 0);
            if (row < N) v = Ag[(size_t)row * 16 + o];
            *(uint4*)&As[r * LD + o * 8] = v;
        }
    }
    __syncthreads();

    constexpr int NG = BN / 16;
    floatx4 acc[NG];
    #pragma unroll
    for (int g = 0; g < NG; ++g) acc[g] = (floatx4){0.f, 0.f, 0.f, 0.f};

    const int arow = wave * 16 + tm;
    #pragma unroll
    for (int kc = 0; kc < 4; ++kc) {
        short8 af = *(const short8*)&As[arow * LD + kc * 32 + q * 8];
        #pragma unroll
        for (int g = 0; g < NG; ++g) {
            short8 bf = *(const short8*)&Bs[(g * 16 + tm) * LD + kc * 32 + q * 8];
            acc[g] = __builtin_amdgcn_mfma_f32_16x16x32_bf16(af, bf, acc[g], 0, 0, 0);
        }
    }

    float dv[4];
    #pragma unroll
    for (int r = 0; r < 4; ++r) {
        int row = row0 + wave * 16 + q * 4 + r;
        dv[r] = (row < N) ? dinv[row] : 0.f;
    }
    #pragma unroll
    for (int g = 0; g < NG; ++g) {
        #pragma unroll
        for (int r = 0; r < 4; ++r) {
            int row = row0 + wave * 16 + q * 4 + r;
            if (row < N) C[(size_t)row * M + g * 16 + tm] = f2bf(dv[r] * acc[g][r]);
        }
    }
}

// ---- aggregation, F=128: lane-parallel row gather (1 row = 1 coalesced VMEM
//      instr), 16-deep pipeline for MLP; pure sum of pre-scaled rows ----
__global__ __launch_bounds__(256) void k_agg128(const unsigned* __restrict__ Hb,
        const float* __restrict__ dinv, const int* __restrict__ rs,
        const int* __restrict__ esrc, const float* __restrict__ bias,
        unsigned* __restrict__ out, int N) {
    int wid = (blockIdx.x * 256 + threadIdx.x) >> 6;
    if (wid >= N) return;
    int l = threadIdx.x & 63;
    float di = dinv[wid];
    unsigned a = Hb[(size_t)wid * 64 + l];         // self row (already dinv-scaled)
    float accx = bf_lo(a), accy = bf_hi(a);
    int k = rs[wid], kend = rs[wid + 1];
    for (; k + 16 <= kend; k += 16) {
        int s[16];
        #pragma unroll
        for (int j = 0; j < 16; ++j) s[j] = esrc[k + j];
        unsigned g[16];
        #pragma unroll
        for (int j = 0; j < 16; ++j) g[j] = Hb[(size_t)s[j] * 64 + l];
        #pragma unroll
        for (int j = 0; j < 16; ++j) { accx += bf_lo(g[j]); accy += bf_hi(g[j]); }
    }
    if (k + 8 <= kend) {
        int s[8];
        #pragma unroll
        for (int j = 0; j < 8; ++j) s[j] = esrc[k + j];
        unsigned g[8];
        #pragma unroll
        for (int j = 0; j < 8; ++j) g[j] = Hb[(size_t)s[j] * 64 + l];
        #pragma unroll
        for (int j = 0; j < 8; ++j) { accx += bf_lo(g[j]); accy += bf_hi(g[j]); }
        k += 8;
    }
    if (k + 4 <= kend) {
        int s[4];
        #pragma unroll
        for (int j = 0; j < 4; ++j) s[j] = esrc[k + j];
        unsigned g[4];
        #pragma unroll
        for (int j = 0; j < 4; ++j) g[j] = Hb[(size_t)s[j] * 64 + l];
        #pragma unroll
        for (int j = 0; j < 4; ++j) { accx += bf_lo(g[j]); accy += bf_hi(g[j]); }
        k += 4;
    }
    for (; k < kend; ++k) {
        unsigned g = Hb[(size_t)esrc[k] * 64 + l];
        accx += bf_lo(g); accy += bf_hi(g);
    }
    float2 b = ((const float2*)bias)[l];
    float ox = fmaxf(fmaf(di, accx, b.x), 0.f);   // layer 1: ReLU
    float oy = fmaxf(fmaf(di, accy, b.y), 0.f);
    out[(size_t)wid * 64 + l] = pack_bf16(ox, oy);
}

// ---- aggregation, F=64: lane-parallel row gather, 16-deep; fp32 out ----
__global__ __launch_bounds__(256) void k_agg64(const unsigned short* __restrict__ Hb,
        const float* __restrict__ dinv, const int* __restrict__ rs,
        const int* __restrict__ esrc, const float* __restrict__ bias,
        float* __restrict__ out, int N) {
    int wid = (blockIdx.x * 256 + threadIdx.x) >> 6;
    if (wid >= N) return;
    int l = threadIdx.x & 63;
    float di = dinv[wid];
    float acc = __uint_as_float((unsigned)Hb[(size_t)wid * 64 + l] << 16);
    int k = rs[wid], kend = rs[wid + 1];
    for (; k + 16 <= kend; k += 16) {
        int s[16];
        #pragma unroll
        for (int j = 0; j < 16; ++j) s[j] = esrc[k + j];
        unsigned short g[16];
        #pragma unroll
        for (int j = 0; j < 16; ++j) g[j] = Hb[(size_t)s[j] * 64 + l];
        #pragma unroll
        for (int j = 0; j < 16; ++j) acc += __uint_as_float((unsigned)g[j] << 16);
    }
    if (k + 8 <= kend) {
        int s[8];
        #pragma unroll
        for (int j = 0; j < 8; ++j) s[j] = esrc[k + j];
        unsigned short g[8];
        #pragma unroll
        for (int j = 0; j < 8; ++j) g[j] = Hb[(size_t)s[j] * 64 + l];
        #pragma unroll
        for (int j = 0; j < 8; ++j) acc += __uint_as_float((unsigned)g[j] << 16);
        k += 8;
    }
    if (k + 4 <= kend) {
        int s[4];
        #pragma unroll
        for (int j = 0; j < 4; ++j) s[j] = esrc[k + j];
        unsigned short g[4];
        #pragma unroll
        for (int j = 0; j < 4; ++j) g[j] = Hb[(size_t)s[j] * 64 + l];
        #pragma unroll
        for (int j = 0; j < 4; ++j) acc += __uint_as_float((unsigned)g[j] << 16);
        k += 4;
    }
    for (; k < kend; ++k)
        acc += __uint_as_float((unsigned)Hb[(size_t)esrc[k] * 64 + l] << 16);
    out[(size_t)wid * 64 + l] = fmaf(di, acc, bias[l]);
}

extern "C" void kernel_launch(void* const* d_in, const int* in_sizes, int n_in,
                              void* d_out, int out_size, void* d_ws, size_t ws_size,
                              hipStream_t stream) {
    const float* x  = (const float*)d_in[0];
    const void*  ei = d_in[1];
    const float* W1 = (const float*)d_in[2];
    const float* b1 = (const float*)d_in[3];
    const float* W2 = (const float*)d_in[4];
    const float* b2 = (const float*)d_in[5];

    int HID = in_sizes[3];            // 128
    int IN  = in_sizes[2] / HID;      // 128
    int OUT = in_sizes[4] / HID;      // 64
    int N   = in_sizes[0] / IN;       // 50000
    int E   = in_sizes[1] / 2;        // 800000
    int NB  = (N + 127) >> BSHIFT;    // dst buckets (391)
    int NC  = (E + CH - 1) / CH;      // chunks (391)

    char* p = (char*)d_ws;
    int* chist     = (int*)p;   p += align256((size_t)NB * NC * 4);
    int* bbase     = (int*)p;   p += align256((size_t)(NB + 1) * 4);
    int* rs_final  = (int*)p;   p += align256((size_t)(N + 1) * 4);
    int* esrc      = (int*)p;   p += align256((size_t)E * 4);
    float* dinv    = (float*)p; p += align256((size_t)N * 4);
    unsigned short* w1t = (unsigned short*)p; p += align256((size_t)HID * IN * 2);
    unsigned short* w2t = (unsigned short*)p; p += align256((size_t)OUT * HID * 2);
    // bbuf (E uint, dead after k_sort) overlays hb (N*HID bf16, written later)
    size_t hb_bytes = (size_t)N * HID * 2, bbuf_bytes = (size_t)E * 4;
    unsigned* bbuf = (unsigned*)p;
    unsigned short* hb = (unsigned short*)p;
    p += align256(hb_bytes > bbuf_bytes ? hb_bytes : bbuf_bytes);
    unsigned short* h1b = (unsigned short*)p; p += align256((size_t)N * HID * 2);
    unsigned short* h2b = (unsigned short*)p; p += align256((size_t)N * OUT * 2);

    // CSR build: hist -> bscan(merged btot) -> hscan2 -> bfill -> sort
    k_hist<<<NC + 2, 256, 0, stream>>>(ei, E, chist, NB, NC,
                                       W1, W2, w1t, w2t, IN, HID, HID, OUT);
    k_bscan<<<1, 1024, 0, stream>>>(chist, bbase, rs_final, NB, NC, N);
    k_hscan2<<<(NB + 3) / 4, 256, 0, stream>>>(chist, bbase, NB, NC);
    k_bfill<<<NC, 256, 0, stream>>>(ei, E, chist, bbuf, NB, NC);
    k_sort<<<NB, 256, 0, stream>>>(bbuf, bbase, rs_final, dinv, esrc, N);

    // layer 1: hb = bf16(dinv * (x @ W1)) ; h1b = bf16(relu(dinv*sum + b1))
    k_gemm<128, true><<<(N + 63) / 64, 256, 0, stream>>>(x, w1t, dinv, hb, N, HID);
    k_agg128<<<(N + 3) / 4, 256, 0, stream>>>((unsigned*)hb, dinv, rs_final, esrc, b1,
                                              (unsigned*)h1b, N);

    // layer 2: h2b = bf16(dinv * (h1b @ W2)) ; out = dinv*sum + b2
    k_gemm<64, false><<<(N + 63) / 64, 256, 0, stream>>>(h1b, w2t, dinv, h2b, N, OUT);
    k_agg64<<<(N + 3) / 4, 256, 0, stream>>>(h2b, dinv, rs_final, esrc, b2, (float*)d_out, N);
}

// Round 12
// 205.802 us; speedup vs baseline: 1.1512x; 1.1512x over previous
//
#include <hip/hip_runtime.h>
#include <stdint.h>

typedef __attribute__((ext_vector_type(8))) short short8;
typedef __attribute__((ext_vector_type(4))) float floatx4;

static inline size_t align256(size_t x) { return (x + 255) & ~size_t(255); }

__device__ __forceinline__ unsigned short f2bf(float f) {
    unsigned u = __float_as_uint(f);
    u += 0x7fff + ((u >> 16) & 1);     // round-to-nearest-even
    return (unsigned short)(u >> 16);
}
__device__ __forceinline__ unsigned pack_bf16(float a, float b) {
    return (unsigned)f2bf(a) | ((unsigned)f2bf(b) << 16);
}
__device__ __forceinline__ float bf_lo(unsigned u) { return __uint_as_float(u << 16); }
__device__ __forceinline__ float bf_hi(unsigned u) { return __uint_as_float(u & 0xffff0000u); }

#define BSHIFT 7     // 128 nodes per dst-bucket
#define NBMAX 1024   // max buckets per LDS window
#define CH 2048      // edges per chunk
#define SCAP 3072    // LDS-staged pairs per bucket
// bbuf packing: (dst&127)<<25 | src  -- requires N < 2^25 (here N=50000)

// per-block edge dtype self-detection: int32 data read as int64 pairs gives
// out-of-range values with prob ~1 per sample; 256 samples => certain.
__device__ __forceinline__ bool detect_i32(const void* eidx, int E, int t) {
    const long long* e64 = (const long long*)eidx;
    int nchk = E < 256 ? E : 256;
    long long v = e64[t % nchk];
    int bad = (v < 0 || v > 0x7fffffffLL) ? 1 : 0;
    return __syncthreads_or(bad) != 0;
}

// ---- chunk x bucket histogram (LDS only); blocks NC/NC+1 convert W1/W2 ----
__global__ __launch_bounds__(256) void k_hist(const void* __restrict__ eidx, int E,
        int* __restrict__ chist, int NB, int NC,
        const float* __restrict__ W1, const float* __restrict__ W2,
        unsigned short* __restrict__ w1t, unsigned short* __restrict__ w2t,
        int K1, int M1, int K2, int M2) {
    __shared__ int hist[NBMAX];
    const int t = threadIdx.x, B = blockIdx.x;
    if (B < NC) {
        const int e0 = B * CH;
        const int e1 = (e0 + CH < E) ? e0 + CH : E;
        const bool i32 = detect_i32(eidx, E, t);
        const int* e32 = (const int*)eidx;
        const long long* e64 = (const long long*)eidx;
        for (int b0 = 0; b0 < NB; b0 += NBMAX) {
            int bw = (NB - b0 < NBMAX) ? NB - b0 : NBMAX;
            for (int i = t; i < bw; i += 256) hist[i] = 0;
            __syncthreads();
            for (int e = e0 + t; e < e1; e += 256) {
                int d = i32 ? e32[(size_t)E + e] : (int)e64[(size_t)E + e];
                int b = (d >> BSHIFT) - b0;
                if (b >= 0 && b < bw) atomicAdd(&hist[b], 1);
            }
            __syncthreads();
            for (int i = t; i < bw; i += 256) chist[(size_t)(b0 + i) * NC + B] = hist[i];
            __syncthreads();
        }
    } else if (B == NC) {
        for (int j = t; j < K1 * M1; j += 256) {
            int k = j / M1, n = j % M1;
            w1t[(size_t)n * K1 + k] = f2bf(W1[j]);
        }
    } else if (B == NC + 1) {
        for (int j = t; j < K2 * M2; j += 256) {
            int k = j / M2, n = j % M2;
            w2t[(size_t)n * K2 + k] = f2bf(W2[j]);
        }
    }
}

// ---- bucket totals: one wave per bucket sums its chist row (98 blocks) ----
__global__ __launch_bounds__(256) void k_btot(const int* __restrict__ chist,
                                              int* __restrict__ btot, int NB, int NC) {
    int b = blockIdx.x * 4 + (threadIdx.x >> 6);
    if (b >= NB) return;
    int lane = threadIdx.x & 63;
    const int* row = chist + (size_t)b * NC;
    int v = 0;
    for (int i = lane; i < NC; i += 64) v += row[i];
    #pragma unroll
    for (int off = 32; off >= 1; off >>= 1) v += __shfl_xor(v, off, 64);
    if (lane == 0) btot[b] = v;
}

// ---- single-block exclusive scan of bucket totals -> bbase[NB+1]; rs_final[N]=E ----
__global__ __launch_bounds__(1024) void k_bscan(const int* __restrict__ btot,
                                                int* __restrict__ bbase,
                                                int* __restrict__ rs_final,
                                                int NB, int N) {
    __shared__ int swt[16];
    const int t = threadIdx.x, lane = t & 63, w = t >> 6;
    int carry = 0;
    for (int base = 0; base < NB; base += 1024) {
        int i = base + t;
        int v = (i < NB) ? btot[i] : 0;
        int incl = v;
        #pragma unroll
        for (int off = 1; off < 64; off <<= 1) {
            int nbr = __shfl_up(incl, off, 64);
            if (lane >= off) incl += nbr;
        }
        if (lane == 63) swt[w] = incl;
        __syncthreads();
        int woff = 0;
        for (int j = 0; j < w; ++j) woff += swt[j];
        if (i < NB) bbase[i] = carry + woff + incl - v;
        int tot = 0;
        for (int j = 0; j < 16; ++j) tot += swt[j];
        carry += tot;
        __syncthreads();
    }
    if (t == 0) { bbase[NB] = carry; rs_final[N] = carry; }
}

// ---- per-bucket chunk scan seeded with bbase: chist[b][c] -> global slot base ----
__global__ __launch_bounds__(256) void k_hscan2(int* __restrict__ chist,
                                                const int* __restrict__ bbase,
                                                int NB, int NC) {
    int b = blockIdx.x * 4 + (threadIdx.x >> 6);
    if (b >= NB) return;
    int lane = threadIdx.x & 63;
    int* row = chist + (size_t)b * NC;
    int carry = bbase[b];
    for (int base = 0; base < NC; base += 64) {
        int i = base + lane;
        int v = (i < NC) ? row[i] : 0;
        int incl = v;
        #pragma unroll
        for (int off = 1; off < 64; off <<= 1) {
            int nbr = __shfl_up(incl, off, 64);
            if (lane >= off) incl += nbr;
        }
        if (i < NC) row[i] = carry + incl - v;
        carry += __shfl(incl, 63, 64);
    }
}

// ---- binned fill: deterministic base + LDS rank; packed uint payload ----
__global__ __launch_bounds__(256) void k_bfill(const void* __restrict__ eidx, int E,
                                               const int* __restrict__ chist,
                                               unsigned* __restrict__ bbuf, int NB, int NC) {
    __shared__ int rank[NBMAX];
    __shared__ int base[NBMAX];
    const int t = threadIdx.x, c = blockIdx.x;
    const int e0 = c * CH;
    const int e1 = (e0 + CH < E) ? e0 + CH : E;
    const bool i32 = detect_i32(eidx, E, t);
    const int* e32 = (const int*)eidx;
    const long long* e64 = (const long long*)eidx;
    for (int b0 = 0; b0 < NB; b0 += NBMAX) {
        int bw = (NB - b0 < NBMAX) ? NB - b0 : NBMAX;
        for (int i = t; i < bw; i += 256) {
            rank[i] = 0;
            base[i] = chist[(size_t)(b0 + i) * NC + c];
        }
        __syncthreads();
        for (int e = e0 + t; e < e1; e += 256) {
            int s, d;
            if (i32) { s = e32[e]; d = e32[(size_t)E + e]; }
            else     { s = (int)e64[e]; d = (int)e64[(size_t)E + e]; }
            int b = (d >> BSHIFT) - b0;
            if (b >= 0 && b < bw) {
                int slot = base[b] + atomicAdd(&rank[b], 1);
                bbuf[slot] = ((unsigned)(d & 127) << 25) | (unsigned)s;
            }
        }
        __syncthreads();
    }
}

// ---- per-bucket LDS counting sort: emits esrc (coalesced), rs_final, dinv ----
__global__ __launch_bounds__(256) void k_sort(const unsigned* __restrict__ bbuf,
                                              const int* __restrict__ bbase,
                                              int* __restrict__ rs_final,
                                              float* __restrict__ dinv,
                                              int* __restrict__ esrc, int N) {
    __shared__ int hist[128];
    __shared__ int off[128];
    __shared__ int srcbuf[SCAP];
    const int b = blockIdx.x, t = threadIdx.x;
    const int node0 = b << BSHIFT;
    const int nloc = (N - node0 < 128) ? N - node0 : 128;
    const int s0 = bbase[b], s1 = bbase[b + 1];
    const int cnt = s1 - s0;
    if (t < 128) hist[t] = 0;
    __syncthreads();
    for (int i = s0 + t; i < s1; i += 256)
        atomicAdd(&hist[bbuf[i] >> 25], 1);
    __syncthreads();
    if (t < 64) {   // wave 0: exclusive scan of 128 counts
        int carry = 0;
        #pragma unroll
        for (int base = 0; base < 128; base += 64) {
            int v = hist[base + t];
            int incl = v;
            #pragma unroll
            for (int o = 1; o < 64; o <<= 1) {
                int nbr = __shfl_up(incl, o, 64);
                if (t >= o) incl += nbr;
            }
            off[base + t] = carry + incl - v;
            carry += __shfl(incl, 63, 64);
        }
    }
    __syncthreads();
    if (t < nloc) {
        rs_final[node0 + t] = s0 + off[t];
        dinv[node0 + t] = rsqrtf((float)hist[t] + 1.0f);
    }
    __syncthreads();
    if (t < 128) hist[t] = 0;   // reuse as rank counters
    __syncthreads();
    if (cnt <= SCAP) {
        for (int i = s0 + t; i < s1; i += 256) {
            unsigned sd = bbuf[i];
            int lo = sd >> 25;
            int r = atomicAdd(&hist[lo], 1);
            srcbuf[off[lo] + r] = (int)(sd & 0x1ffffffu);
        }
        __syncthreads();
        for (int i = t; i < cnt; i += 256) esrc[s0 + i] = srcbuf[i];
    } else {        // fallback: scatter within bucket's global window
        for (int i = s0 + t; i < s1; i += 256) {
            unsigned sd = bbuf[i];
            int lo = sd >> 25;
            int r = atomicAdd(&hist[lo], 1);
            esrc[s0 + off[lo] + r] = (int)(sd & 0x1ffffffu);
        }
    }
}

// ============================================================================
// bf16 MFMA GEMM, tile 64 rows x BN cols (BN == M), K=128 one LDS stage.
// AF32: A is fp32, converted during staging. Epilogue folds dinv.
// ============================================================================
template<int BN, bool AF32>
__global__ __launch_bounds__(256, 3) void k_gemm(
        const void* __restrict__ Av, const unsigned short* __restrict__ Bt,
        const float* __restrict__ dinv, unsigned short* __restrict__ C,
        int N, int M) {
    constexpr int LD = 136;               // 128 + 8 u16 pad
    __shared__ unsigned short As[64 * LD];
    __shared__ unsigned short Bs[BN * LD];
    const int tid = threadIdx.x;
    const int wave = tid >> 6, lane = tid & 63;
    const int q = lane >> 4, tm = lane & 15;
    const int row0 = blockIdx.x * 64;

    {   // stage Bt rows [0,BN)
        const uint4* Bg = (const uint4*)Bt;
        #pragma unroll
        for (int it = 0; it < BN / 16; ++it) {
            int i = tid + it * 256;
            int r = i >> 4, o = i & 15;
            *(uint4*)&Bs[r * LD + o * 8] = Bg[(size_t)r * 16 + o];
        }
    }
    if (AF32) {   // stage A rows with inline fp32->bf16
        const float4* Ag = (const float4*)Av;
        #pragma unroll
        for (int it = 0; it < 8; ++it) {
            int i = tid + it * 256;
            int r = i >> 5, o = i & 31;
            int row = row0 + r;
            float4 v = make_float4(0.f, 0.f, 0.f, 0.f);
            if (row < N) v = Ag[(size_t)row * 32 + o];
            uint2 pk;
            pk.x = pack_bf16(v.x, v.y);
            pk.y = pack_bf16(v.z, v.w);
            *(uint2*)&As[r * LD + o * 4] = pk;
        }
    } else {      // stage bf16 A rows
        const uint4* Ag = (const uint4*)Av;
        #pragma unroll
        for (int it = 0; it < 4; ++it) {
            int i = tid + it * 256;
            int r = i >> 4, o = i & 15;
            int row = row0 + r;
            uint4 v = make_uint4(0, 0, 0, 0);
            if (row < N) v = Ag[(size_t)row * 16 + o];
            *(uint4*)&As[r * LD + o * 8] = v;
        }
    }
    __syncthreads();

    constexpr int NG = BN / 16;
    floatx4 acc[NG];
    #pragma unroll
    for (int g = 0; g < NG; ++g) acc[g] = (floatx4){0.f, 0.f, 0.f, 0.f};

    const int arow = wave * 16 + tm;
    #pragma unroll
    for (int kc = 0; kc < 4; ++kc) {
        short8 af = *(const short8*)&As[arow * LD + kc * 32 + q * 8];
        #pragma unroll
        for (int g = 0; g < NG; ++g) {
            short8 bf = *(const short8*)&Bs[(g * 16 + tm) * LD + kc * 32 + q * 8];
            acc[g] = __builtin_amdgcn_mfma_f32_16x16x32_bf16(af, bf, acc[g], 0, 0, 0);
        }
    }

    float dv[4];
    #pragma unroll
    for (int r = 0; r < 4; ++r) {
        int row = row0 + wave * 16 + q * 4 + r;
        dv[r] = (row < N) ? dinv[row] : 0.f;
    }
    #pragma unroll
    for (int g = 0; g < NG; ++g) {
        #pragma unroll
        for (int r = 0; r < 4; ++r) {
            int row = row0 + wave * 16 + q * 4 + r;
            if (row < N) C[(size_t)row * M + g * 16 + tm] = f2bf(dv[r] * acc[g][r]);
        }
    }
}

// ---- aggregation, F=128: pure gather-sum of pre-scaled rows; 8-deep pipeline ----
__global__ __launch_bounds__(256) void k_agg128(const unsigned* __restrict__ Hb,
        const float* __restrict__ dinv, const int* __restrict__ rs,
        const int* __restrict__ esrc, const float* __restrict__ bias,
        unsigned* __restrict__ out, int N) {
    int wid = (blockIdx.x * 256 + threadIdx.x) >> 6;
    if (wid >= N) return;
    int l = threadIdx.x & 63;
    float di = dinv[wid];
    unsigned a = Hb[(size_t)wid * 64 + l];         // self row (already dinv-scaled)
    float accx = bf_lo(a), accy = bf_hi(a);
    int k = rs[wid], kend = rs[wid + 1];
    for (; k + 8 <= kend; k += 8) {
        int s[8];
        #pragma unroll
        for (int j = 0; j < 8; ++j) s[j] = esrc[k + j];   // wave-uniform -> scalar loads
        unsigned g[8];
        #pragma unroll
        for (int j = 0; j < 8; ++j) g[j] = Hb[(size_t)s[j] * 64 + l];
        #pragma unroll
        for (int j = 0; j < 8; ++j) { accx += bf_lo(g[j]); accy += bf_hi(g[j]); }
    }
    if (k + 4 <= kend) {
        int s[4];
        #pragma unroll
        for (int j = 0; j < 4; ++j) s[j] = esrc[k + j];
        unsigned g[4];
        #pragma unroll
        for (int j = 0; j < 4; ++j) g[j] = Hb[(size_t)s[j] * 64 + l];
        #pragma unroll
        for (int j = 0; j < 4; ++j) { accx += bf_lo(g[j]); accy += bf_hi(g[j]); }
        k += 4;
    }
    for (; k < kend; ++k) {
        unsigned g = Hb[(size_t)esrc[k] * 64 + l];
        accx += bf_lo(g); accy += bf_hi(g);
    }
    float2 b = ((const float2*)bias)[l];
    float ox = fmaxf(fmaf(di, accx, b.x), 0.f);   // layer 1: ReLU
    float oy = fmaxf(fmaf(di, accy, b.y), 0.f);
    out[(size_t)wid * 64 + l] = pack_bf16(ox, oy);
}

// ---- aggregation, F=64: pure gather-sum; fp32 out (+bias) ----
__global__ __launch_bounds__(256) void k_agg64(const unsigned short* __restrict__ Hb,
        const float* __restrict__ dinv, const int* __restrict__ rs,
        const int* __restrict__ esrc, const float* __restrict__ bias,
        float* __restrict__ out, int N) {
    int wid = (blockIdx.x * 256 + threadIdx.x) >> 6;
    if (wid >= N) return;
    int l = threadIdx.x & 63;
    float di = dinv[wid];
    float acc = __uint_as_float((unsigned)Hb[(size_t)wid * 64 + l] << 16);
    int k = rs[wid], kend = rs[wid + 1];
    for (; k + 8 <= kend; k += 8) {
        int s[8];
        #pragma unroll
        for (int j = 0; j < 8; ++j) s[j] = esrc[k + j];
        unsigned short g[8];
        #pragma unroll
        for (int j = 0; j < 8; ++j) g[j] = Hb[(size_t)s[j] * 64 + l];
        #pragma unroll
        for (int j = 0; j < 8; ++j) acc += __uint_as_float((unsigned)g[j] << 16);
    }
    if (k + 4 <= kend) {
        int s[4];
        #pragma unroll
        for (int j = 0; j < 4; ++j) s[j] = esrc[k + j];
        unsigned short g[4];
        #pragma unroll
        for (int j = 0; j < 4; ++j) g[j] = Hb[(size_t)s[j] * 64 + l];
        #pragma unroll
        for (int j = 0; j < 4; ++j) acc += __uint_as_float((unsigned)g[j] << 16);
        k += 4;
    }
    for (; k < kend; ++k)
        acc += __uint_as_float((unsigned)Hb[(size_t)esrc[k] * 64 + l] << 16);
    out[(size_t)wid * 64 + l] = fmaf(di, acc, bias[l]);
}

extern "C" void kernel_launch(void* const* d_in, const int* in_sizes, int n_in,
                              void* d_out, int out_size, void* d_ws, size_t ws_size,
                              hipStream_t stream) {
    const float* x  = (const float*)d_in[0];
    const void*  ei = d_in[1];
    const float* W1 = (const float*)d_in[2];
    const float* b1 = (const float*)d_in[3];
    const float* W2 = (const float*)d_in[4];
    const float* b2 = (const float*)d_in[5];

    int HID = in_sizes[3];            // 128
    int IN  = in_sizes[2] / HID;      // 128
    int OUT = in_sizes[4] / HID;      // 64
    int N   = in_sizes[0] / IN;       // 50000
    int E   = in_sizes[1] / 2;        // 800000
    int NB  = (N + 127) >> BSHIFT;    // dst buckets (391)
    int NC  = (E + CH - 1) / CH;      // chunks (391)

    char* p = (char*)d_ws;
    int* chist     = (int*)p;   p += align256((size_t)NB * NC * 4);
    int* btot      = (int*)p;   p += align256((size_t)NB * 4);
    int* bbase     = (int*)p;   p += align256((size_t)(NB + 1) * 4);
    int* rs_final  = (int*)p;   p += align256((size_t)(N + 1) * 4);
    int* esrc      = (int*)p;   p += align256((size_t)E * 4);
    float* dinv    = (float*)p; p += align256((size_t)N * 4);
    unsigned short* w1t = (unsigned short*)p; p += align256((size_t)HID * IN * 2);
    unsigned short* w2t = (unsigned short*)p; p += align256((size_t)OUT * HID * 2);
    // bbuf (E uint, dead after k_sort) overlays hb (N*HID bf16, written later)
    size_t hb_bytes = (size_t)N * HID * 2, bbuf_bytes = (size_t)E * 4;
    unsigned* bbuf = (unsigned*)p;
    unsigned short* hb = (unsigned short*)p;
    p += align256(hb_bytes > bbuf_bytes ? hb_bytes : bbuf_bytes);
    unsigned short* h1b = (unsigned short*)p; p += align256((size_t)N * HID * 2);
    unsigned short* h2b = (unsigned short*)p; p += align256((size_t)N * OUT * 2);

    // CSR build: hist -> btot -> bscan -> hscan2 -> bfill -> sort
    k_hist<<<NC + 2, 256, 0, stream>>>(ei, E, chist, NB, NC,
                                       W1, W2, w1t, w2t, IN, HID, HID, OUT);
    k_btot<<<(NB + 3) / 4, 256, 0, stream>>>(chist, btot, NB, NC);
    k_bscan<<<1, 1024, 0, stream>>>(btot, bbase, rs_final, NB, N);
    k_hscan2<<<(NB + 3) / 4, 256, 0, stream>>>(chist, bbase, NB, NC);
    k_bfill<<<NC, 256, 0, stream>>>(ei, E, chist, bbuf, NB, NC);
    k_sort<<<NB, 256, 0, stream>>>(bbuf, bbase, rs_final, dinv, esrc, N);

    // layer 1: hb = bf16(dinv * (x @ W1)) ; h1b = bf16(relu(dinv*sum + b1))
    k_gemm<128, true><<<(N + 63) / 64, 256, 0, stream>>>(x, w1t, dinv, hb, N, HID);
    k_agg128<<<(N + 3) / 4, 256, 0, stream>>>((unsigned*)hb, dinv, rs_final, esrc, b1,
                                              (unsigned*)h1b, N);

    // layer 2: h2b = bf16(dinv * (h1b @ W2)) ; out = dinv*sum + b2
    k_gemm<64, false><<<(N + 63) / 64, 256, 0, stream>>>(h1b, w2t, dinv, h2b, N, OUT);
    k_agg64<<<(N + 3) / 4, 256, 0, stream>>>(h2b, dinv, rs_final, esrc, b2, (float*)d_out, N);
}